// Round 2
// baseline (205.334 us; speedup 1.0000x reference)
//
#include <hip/hip_runtime.h>
#include <math.h>

// out[b] = log( sum_{kk in [0,65536)} w[kk>>8] * W0[kk, x0[b]] * W1[kk, x1[b]] )
//
// v3: pure split-k (256 blocks, 1/CU, block = one latent k so w is
// block-uniform) + register double-buffered staging: iteration it+1's
// global loads are issued before it's convert/MFMA phases, so the HBM
// transfer overlaps the barrier+convert+ds_read+MFMA pipeline instead of
// serializing with it. W is read exactly once (134 MB = the HBM floor).
// Epilogue gathers the 1024 needed (x0,x1) cells through a 64-row LDS
// quarter-tile; finish does a coalesced row-sum + log.

#define KCHUNK 256
#define BK     32
#define NITER  (KCHUNK / BK)   // 8
#define LDSS   40              // shorts per c-row: 32 k + 8 pad = 80 B

typedef float  f32x4  __attribute__((ext_vector_type(4)));
typedef short  bf16x8 __attribute__((ext_vector_type(8)));

static __device__ __forceinline__ short f2bf(float f) {
    // RNE fp32 -> bf16 (inputs are positive probabilities; no NaN/Inf)
    unsigned u = __builtin_bit_cast(unsigned, f);
    u += 0x7fffu + ((u >> 16) & 1u);
    return (short)(u >> 16);
}

__global__ __launch_bounds__(512, 2) void gemm_gather_kernel(
    const int* __restrict__ x, const float* __restrict__ W,
    const float* __restrict__ wsum, float* __restrict__ G)
{
    extern __shared__ char smem[];
    short* __restrict__ As = (short*)smem;                      // [256][LDSS]
    short* __restrict__ Bs = (short*)(smem + 256 * LDSS * 2);   // [256][LDSS]
    float* __restrict__ Sg = (float*)smem;                      // [64][256] epilogue alias

    const int  split = blockIdx.x;                 // 0..255 == latent k
    const long kbase = (long)split * KCHUNK;
    const float* __restrict__ Ag = W + kbase * 256;              // W0 chunk
    const float* __restrict__ Bg = W + 16777216 + kbase * 256;   // W1 chunk

    const int t  = threadIdx.x;
    // staging: 64 c-quads x 8 k-rows, r=0..3 -> 4 float4 per operand per thread
    const int cq = (t & 63) * 4;
    const int kq = (t >> 6) * 4;

    const int lane = t & 63;
    const int wv   = t >> 6;             // wave 0..7
    const int wc0  = (wv & 3) * 64;      // 4 wave-tiles along c0
    const int wc1  = (wv >> 2) * 128;    // 2 along c1
    const int ml   = lane & 15;
    const int qd   = lane >> 4;

    f32x4 acc[4][8];
#pragma unroll
    for (int i = 0; i < 4; ++i)
#pragma unroll
        for (int j = 0; j < 8; ++j) acc[i][j] = (f32x4){0.f, 0.f, 0.f, 0.f};

#define LOAD(Aset, Bset, it_)                                                  \
    do {                                                                       \
        _Pragma("unroll")                                                      \
        for (int r = 0; r < 4; ++r) {                                          \
            Aset[r] = *(const float4*)(Ag + (long)((it_) * BK + kq + r) * 256 + cq); \
            Bset[r] = *(const float4*)(Bg + (long)((it_) * BK + kq + r) * 256 + cq); \
        }                                                                      \
    } while (0)

#define STAGE(Aset, Bset)                                                      \
    do {                                                                       \
        const float* af_ = reinterpret_cast<const float*>(Aset);               \
        const float* bf_ = reinterpret_cast<const float*>(Bset);               \
        _Pragma("unroll")                                                      \
        for (int j = 0; j < 4; ++j) {                                          \
            short4 av, bv;                                                     \
            av.x = f2bf(af_[0 * 4 + j]);                                       \
            av.y = f2bf(af_[1 * 4 + j]);                                       \
            av.z = f2bf(af_[2 * 4 + j]);                                       \
            av.w = f2bf(af_[3 * 4 + j]);                                       \
            *(short4*)&As[(cq + j) * LDSS + kq] = av;                          \
            bv.x = f2bf(bf_[0 * 4 + j]);                                       \
            bv.y = f2bf(bf_[1 * 4 + j]);                                       \
            bv.z = f2bf(bf_[2 * 4 + j]);                                       \
            bv.w = f2bf(bf_[3 * 4 + j]);                                       \
            *(short4*)&Bs[(cq + j) * LDSS + kq] = bv;                          \
        }                                                                      \
    } while (0)

#define COMPUTE()                                                              \
    do {                                                                       \
        bf16x8 afr[4];                                                         \
        _Pragma("unroll")                                                      \
        for (int mi = 0; mi < 4; ++mi)                                         \
            afr[mi] = *(const bf16x8*)&As[(wc0 + mi * 16 + ml) * LDSS + qd * 8]; \
        _Pragma("unroll")                                                      \
        for (int ni = 0; ni < 8; ++ni) {                                       \
            const bf16x8 bfr = *(const bf16x8*)&Bs[(wc1 + ni * 16 + ml) * LDSS + qd * 8]; \
            _Pragma("unroll")                                                  \
            for (int mi = 0; mi < 4; ++mi)                                     \
                acc[mi][ni] = __builtin_amdgcn_mfma_f32_16x16x32_bf16(         \
                    afr[mi], bfr, acc[mi][ni], 0, 0, 0);                       \
        }                                                                      \
    } while (0)

    float4 A0[4], B0[4], A1[4], B1[4];
    LOAD(A0, B0, 0);
#pragma unroll
    for (int it = 0; it < NITER; it += 2) {
        // issue it+1's loads ASAP: they ride out {barrier, STAGE, barrier,
        // COMPUTE} before being consumed — a full iteration of latency cover
        LOAD(A1, B1, it + 1);                    // it+1 <= 7 always valid
        __syncthreads();                         // prior COMPUTE's LDS reads done
        STAGE(A0, B0);                           // waits on A0/B0 vmcnt only
        __syncthreads();
        COMPUTE();                               // it

        if (it + 2 < NITER) LOAD(A0, B0, it + 2);
        __syncthreads();
        STAGE(A1, B1);
        __syncthreads();
        COMPUTE();                               // it+1
    }
#undef LOAD
#undef STAGE
#undef COMPUTE

    // Epilogue: gather the 1024 needed cells of this block's 256x256 tile.
    // C/D layout: col = lane&15, row = (lane>>4)*4 + reg (harness-verified).
    // 4 rounds of 64 c0-rows; waves with wc0==q*64 dump into LDS, everyone looks up.
    const int b0 = t, b1 = t + 512;
    const int2 xa = ((const int2*)x)[b0];   // coalesced (x0, x1) pairs
    const int2 xb = ((const int2*)x)[b1];
    float v0 = 0.f, v1 = 0.f;
#pragma unroll
    for (int q = 0; q < 4; ++q) {
        __syncthreads();                    // prior round's reads complete
        if (wc0 == q * 64) {
#pragma unroll
            for (int mi = 0; mi < 4; ++mi)
#pragma unroll
                for (int ni = 0; ni < 8; ++ni)
#pragma unroll
                    for (int r = 0; r < 4; ++r)
                        Sg[(mi * 16 + qd * 4 + r) * 256 + wc1 + ni * 16 + ml] =
                            acc[mi][ni][r];
        }
        __syncthreads();
        if ((xa.x >> 6) == q) v0 = Sg[(xa.x & 63) * 256 + xa.y];
        if ((xb.x >> 6) == q) v1 = Sg[(xb.x & 63) * 256 + xb.y];
    }
    const float w = wsum[split];            // block-uniform, applied once in f32
    G[(long)b0 * 256 + split] = v0 * w;
    G[(long)b1 * 256 + split] = v1 * w;
}

// One wave per b: contiguous 1 KB row of G, float4 loads, shuffle-reduce, log.
__global__ __launch_bounds__(256) void finish_kernel(
    const float* __restrict__ G, float* __restrict__ out)
{
    const int b    = blockIdx.x * 4 + (threadIdx.x >> 6);
    const int lane = threadIdx.x & 63;
    const float4 g = ((const float4*)(G + (long)b * 256))[lane];
    float v = (g.x + g.y) + (g.z + g.w);
#pragma unroll
    for (int off = 32; off > 0; off >>= 1) v += __shfl_down(v, off);
    if (lane == 0) out[b] = logf(v);
}

extern "C" void kernel_launch(void* const* d_in, const int* in_sizes, int n_in,
                              void* d_out, int out_size, void* d_ws, size_t ws_size,
                              hipStream_t stream)
{
    const int*   x    = (const int*)d_in[0];     // [1024,2] int32
    const float* W    = (const float*)d_in[1];   // [2,256,256,256] fp32
    const float* wsum = (const float*)d_in[2];   // [256] fp32
    float* G   = (float*)d_ws;                   // [1024][256] f32 = 1 MB
    float* out = (float*)d_out;                  // [1024] fp32

    gemm_gather_kernel<<<dim3(256), 512, 65536, stream>>>(x, W, wsum, G);
    finish_kernel<<<dim3(256), 256, 0, stream>>>(G, out);
}